// Round 2
// baseline (476.697 us; speedup 1.0000x reference)
//
#include <hip/hip_runtime.h>
#include <hip/hip_bf16.h>

#define B_SZ 16384
#define NA 308
#define NAP 320
#define UN 512

typedef float f32x4 __attribute__((ext_vector_type(4)));
typedef short bf16x8 __attribute__((ext_vector_type(8)));
typedef unsigned short ushort_t;

// ---------------- ws layout (bytes) ----------------
constexpr size_t OFF_WB0 = 0;                       // 1536*320*2 = 983040
constexpr size_t OFF_WB1 = 0x100000;                // 1536*512*2 = 1572864
constexpr size_t OFF_WB2 = 0x280000;                // 1572864
constexpr size_t OFF_WOB = 0x400000;                // 320*512*2 = 327680
constexpr size_t OFF_B0R = 0x480000;                // 1536*4
constexpr size_t OFF_B1R = OFF_B0R + 0x2000;
constexpr size_t OFF_B2R = OFF_B1R + 0x2000;
constexpr size_t OFF_A0  = OFF_B2R + 0x2000;        // 308*4*4
constexpr size_t OFF_C0  = OFF_A0  + 0x2000;        // 308*4
constexpr size_t OFF_A1  = OFF_C0  + 0x2000;        // 512*4*4 = 8192
constexpr size_t OFF_C1  = OFF_A1  + 0x2000;
constexpr size_t OFF_A2  = OFF_C1  + 0x2000;
constexpr size_t OFF_C2  = OFF_A2  + 0x2000;
constexpr size_t OFF_XA  = 0x500000;                // 16384*512*2 = 16 MiB (layer-0 uses [16384][320] prefix)
constexpr size_t OFF_XB  = OFF_XA + 0x1000000;      // 16 MiB; total ws need = 0x2500000 ≈ 38.8 MB

__device__ __forceinline__ float sigmoidf_(float x){ return 1.0f/(1.0f+__expf(-x)); }
__device__ __forceinline__ float tanhf_(float x){ return 2.0f/(1.0f+__expf(-2.0f*x)) - 1.0f; }

__device__ __forceinline__ ushort_t f2b(float f){
  union { float f; unsigned int u; } v; v.f = f;
  unsigned int r = v.u + 0x7FFFu + ((v.u >> 16) & 1u);
  return (ushort_t)(r >> 16);
}

__device__ __forceinline__ void gload16(const void* g, void* l){
  __builtin_amdgcn_global_load_lds((__attribute__((address_space(1))) void*)(g),
                                   (__attribute__((address_space(3))) void*)(l), 16, 0, 0);
}

// reordered gate row: n in [0,1536) laid out as [jb(8)][t(3: i,g,o)][r(64)]
__device__ __forceinline__ int gate_srow(int n){
  int jb = n / 192; int rem = n - jb*192; int t = rem >> 6; int r = rem & 63;
  int g = (t == 0) ? 0 : ((t == 1) ? 1024 : 1536);   // PyTorch order i,f,g,o ; f skipped (c_prev=0)
  return g + jb*64 + r;
}

// ---------------- prep: weights -> bf16 (reordered, K-padded), bias sums, style composition ----------------
__global__ void prep_kernel(
    const float* __restrict__ Wih0, const float* __restrict__ Wih1, const float* __restrict__ Wih2,
    const float* __restrict__ Wout,
    const float* __restrict__ bih0, const float* __restrict__ bhh0,
    const float* __restrict__ bih1, const float* __restrict__ bhh1,
    const float* __restrict__ bih2, const float* __restrict__ bhh2,
    const float* __restrict__ Wsl, const float* __restrict__ bsl,
    const float* __restrict__ Ws0, const float* __restrict__ bs0,
    const float* __restrict__ Ws1, const float* __restrict__ bs1,
    const float* __restrict__ Ws2, const float* __restrict__ bs2,
    char* __restrict__ ws)
{
  const int tid = blockIdx.x*blockDim.x + threadIdx.x;
  const int stride = gridDim.x*blockDim.x;

  const float* WihA[3] = {Wih0, Wih1, Wih2};
  const float* bihA[3] = {bih0, bih1, bih2};
  const float* bhhA[3] = {bhh0, bhh1, bhh2};
  const float* WsA[3]  = {Ws0, Ws1, Ws2};
  const float* bsA[3]  = {bs0, bs1, bs2};
  const int KpA[3] = {NAP, UN, UN};
  const int KrA[3] = {NA, UN, UN};
  const size_t wbOff[3] = {OFF_WB0, OFF_WB1, OFF_WB2};
  const size_t bOff[3]  = {OFF_B0R, OFF_B1R, OFF_B2R};
  const size_t aOff[3]  = {OFF_A0, OFF_A1, OFF_A2};
  const size_t cOff[3]  = {OFF_C0, OFF_C1, OFF_C2};

  #pragma unroll
  for (int ly = 0; ly < 3; ly++){
    ushort_t* dst = (ushort_t*)(ws + wbOff[ly]);
    const float* Wih = WihA[ly];
    const int Kp = KpA[ly], Kr = KrA[ly];
    const int tot = 1536*Kp;
    for (int i = tid; i < tot; i += stride){
      int n = i / Kp, k = i - n*Kp;
      int srow = gate_srow(n);
      float v = (k < Kr) ? Wih[(size_t)srow*Kr + k] : 0.0f;
      dst[i] = f2b(v);
    }
  }
  { // Wout -> bf16, rows padded 308->320
    ushort_t* dst = (ushort_t*)(ws + OFF_WOB);
    for (int i = tid; i < 320*512; i += stride){
      int n = i >> 9, k = i & 511;
      dst[i] = f2b(n < NA ? Wout[(size_t)n*UN + k] : 0.0f);
    }
  }
  #pragma unroll
  for (int ly = 0; ly < 3; ly++){ // bih+bhh, reordered
    float* bd = (float*)(ws + bOff[ly]);
    for (int i = tid; i < 1536; i += stride){
      int srow = gate_srow(i);
      bd[i] = bihA[ly][srow] + bhhA[ly][srow];
    }
  }
  #pragma unroll
  for (int ly = 0; ly < 3; ly++){ // A_l = Ws_l @ Wsl  [N][4];  c_l = Ws_l @ bsl + bs_l
    float* Ad = (float*)(ws + aOff[ly]);
    float* cd = (float*)(ws + cOff[ly]);
    const float* Wsp = WsA[ly]; const float* bsp = bsA[ly];
    const int N = (ly == 0) ? NA : UN;
    for (int i = tid; i < N*4; i += stride){
      int n = i >> 2, q = i & 3;
      float s = 0.f;
      #pragma unroll 8
      for (int j = 0; j < 32; j++) s += Wsp[n*32 + j] * Wsl[j*4 + q];
      Ad[i] = s;
    }
    for (int i = tid; i < N; i += stride){
      float s = 0.f;
      #pragma unroll 8
      for (int j = 0; j < 32; j++) s += Wsp[i*32 + j] * bsl[j];
      cd[i] = s + bsp[i];
    }
  }
}

// ---------------- b0: x0 = bf16(x + tanh(style·A0 + c0)), padded to 320 cols ----------------
__global__ void b0_kernel(const float* __restrict__ x, const float* __restrict__ style,
                          const float* __restrict__ A0, const float* __restrict__ c0,
                          ushort_t* __restrict__ x0b)
{
  int idx = blockIdx.x*blockDim.x + threadIdx.x;
  const int total = B_SZ * (NAP/8);
  const int stride = gridDim.x*blockDim.x;
  for (int i = idx; i < total; i += stride){
    int b = i / 40;
    int kc = (i - b*40) * 8;
    float4 sty = *(const float4*)(style + b*4);
    unsigned int pk[4];
    #pragma unroll
    for (int h = 0; h < 4; h++){
      ushort_t lo = 0, hi = 0;
      int k0 = kc + h*2;
      if (k0 < NA){
        float4 A = *(const float4*)(A0 + k0*4);
        float tt = sty.x*A.x + sty.y*A.y + sty.z*A.z + sty.w*A.w + c0[k0];
        lo = f2b(x[(size_t)b*NA + k0] + tanhf_(tt));
      }
      if (k0 + 1 < NA){
        float4 A = *(const float4*)(A0 + (k0+1)*4);
        float tt = sty.x*A.x + sty.y*A.y + sty.z*A.z + sty.w*A.w + c0[k0+1];
        hi = f2b(x[(size_t)b*NA + k0 + 1] + tanhf_(tt));
      }
      pk[h] = (unsigned int)lo | ((unsigned int)hi << 16);
    }
    *(uint4*)(x0b + (size_t)i*8) = make_uint4(pk[0], pk[1], pk[2], pk[3]);
  }
}

// ---------------- fused gates GEMM: gates = Xb @ Wb.T (+bias) -> h,c ; epilogue builds next-layer input ----
// MODE 0: xnext = h + tanh(style·Anext + cnext)
// MODE 1: xnext = h + hp0 + tanh(style·Anext + cnext)
// MODE 2: xnext = h + hp0 + hp1
template<int MODE>
__global__ __launch_bounds__(512, 2)
void gates_kernel(const ushort_t* __restrict__ Xb, int Kpad,
                  const ushort_t* __restrict__ Wb,       // [8][3][64][Kpad] bf16
                  const float* __restrict__ biasr,       // [8][3][64]
                  float* __restrict__ h_out, float* __restrict__ c_out,
                  const float* __restrict__ style,
                  const float* __restrict__ Anext, const float* __restrict__ cnext,
                  const float* __restrict__ hp0, const float* __restrict__ hp1,
                  ushort_t* __restrict__ xnext)
{
  __shared__ char smem[40960];
  char* ldsX = smem;           // [128][64] bf16, 128B rows, XOR-swizzled granules
  char* ldsW = smem + 16384;   // [192][64] bf16

  const int tid = threadIdx.x;
  const int l = tid & 63;
  const int w = tid >> 6;          // 8 waves: 4 (rows) x 2 (j-cols)
  const int wm = w >> 1, wn = w & 1;
  const int m0 = blockIdx.x * 128;
  const int jb = blockIdx.y;       // 64 h-cols per block

  // per-lane fragment LDS offsets (constant across K steps). swizzle: granule c -> c ^ (row&7)
  int aoff[2][2], boff[3][2][2];
  #pragma unroll
  for (int mi = 0; mi < 2; mi++){
    int r = wm*32 + mi*16 + (l & 15);
    #pragma unroll
    for (int ks = 0; ks < 2; ks++){
      int c = ks*4 + (l >> 4);
      aoff[mi][ks] = r*128 + ((c ^ (r & 7)) << 4);
    }
  }
  #pragma unroll
  for (int t = 0; t < 3; t++)
    #pragma unroll
    for (int ni = 0; ni < 2; ni++){
      int rr = t*64 + wn*32 + ni*16 + (l & 15);
      #pragma unroll
      for (int ks = 0; ks < 2; ks++){
        int c = ks*4 + (l >> 4);
        boff[t][ni][ks] = rr*128 + ((c ^ (rr & 7)) << 4);
      }
    }

  f32x4 acc[3][2][2] = {};
  const int KT = Kpad >> 6;

  for (int kt = 0; kt < KT; kt++){
    const int k0 = kt << 6;
    // stage X tile: 1024 granules of 16B (linear LDS dest, inverse-swizzled global src)
    #pragma unroll
    for (int it = 0; it < 2; it++){
      int g = it*512 + tid;
      int row = g >> 3, c = g & 7, cs = c ^ (row & 7);
      gload16(Xb + (size_t)(m0 + row)*Kpad + k0 + cs*8, ldsX + g*16);
    }
    // stage W tile: 1536 granules
    #pragma unroll
    for (int it = 0; it < 3; it++){
      int g = it*512 + tid;
      int row = g >> 3, c = g & 7, cs = c ^ (row & 7);
      gload16(Wb + (size_t)(jb*192 + row)*Kpad + k0 + cs*8, ldsW + g*16);
    }
    __syncthreads();   // compiler drains vmcnt before barrier

    bf16x8 a[2][2];
    #pragma unroll
    for (int mi = 0; mi < 2; mi++)
      #pragma unroll
      for (int ks = 0; ks < 2; ks++)
        a[mi][ks] = *(const bf16x8*)(ldsX + aoff[mi][ks]);

    #pragma unroll
    for (int t = 0; t < 3; t++){
      bf16x8 bb[2][2];
      #pragma unroll
      for (int ni = 0; ni < 2; ni++)
        #pragma unroll
        for (int ks = 0; ks < 2; ks++)
          bb[ni][ks] = *(const bf16x8*)(ldsW + boff[t][ni][ks]);
      #pragma unroll
      for (int mi = 0; mi < 2; mi++)
        #pragma unroll
        for (int ni = 0; ni < 2; ni++){
          acc[t][mi][ni] = __builtin_amdgcn_mfma_f32_16x16x32_bf16(a[mi][0], bb[ni][0], acc[t][mi][ni], 0, 0, 0);
          acc[t][mi][ni] = __builtin_amdgcn_mfma_f32_16x16x32_bf16(a[mi][1], bb[ni][1], acc[t][mi][ni], 0, 0, 0);
        }
    }
    __syncthreads();
  }

  // epilogue: activations, h/c stores, fused next-layer input
  #pragma unroll
  for (int ni = 0; ni < 2; ni++){
    int jl = wn*32 + ni*16 + (l & 15);
    int j = jb*64 + jl;
    float bi = biasr[jb*192 + jl];
    float bg = biasr[jb*192 + 64 + jl];
    float bo = biasr[jb*192 + 128 + jl];
    float4 An = {0,0,0,0}; float cn = 0.f;
    if constexpr (MODE == 0 || MODE == 1){
      An = *(const float4*)(Anext + j*4);
      cn = cnext[j];
    }
    #pragma unroll
    for (int mi = 0; mi < 2; mi++){
      #pragma unroll
      for (int reg = 0; reg < 4; reg++){
        int m = m0 + wm*32 + mi*16 + ((l >> 4) << 2) + reg;
        float gi = acc[0][mi][ni][reg] + bi;
        float gg = acc[1][mi][ni][reg] + bg;
        float go = acc[2][mi][ni][reg] + bo;
        float iv = sigmoidf_(gi);
        float gv = tanhf_(gg);
        float ov = sigmoidf_(go);
        float cv = iv * gv;              // c_prev = 0 -> f-gate dead
        float hv = ov * tanhf_(cv);
        size_t o = (size_t)m*UN + j;
        c_out[o] = cv;
        h_out[o] = hv;
        float nx = hv;
        if constexpr (MODE == 0){
          float4 sty = *(const float4*)(style + m*4);
          nx += tanhf_(sty.x*An.x + sty.y*An.y + sty.z*An.z + sty.w*An.w + cn);
        } else if constexpr (MODE == 1){
          float4 sty = *(const float4*)(style + m*4);
          nx += hp0[o] + tanhf_(sty.x*An.x + sty.y*An.y + sty.z*An.z + sty.w*An.w + cn);
        } else {
          nx += hp0[o] + hp1[o];
        }
        xnext[o] = f2b(nx);
      }
    }
  }
}

// ---------------- out = Xf @ Wout.T + bout ----------------
__global__ __launch_bounds__(512, 2)
void out_kernel(const ushort_t* __restrict__ Xb,
                const ushort_t* __restrict__ Wob,   // [320][512] bf16 (rows >=308 zero)
                const float* __restrict__ bout,
                float* __restrict__ out)
{
  __shared__ char smem[24576];
  char* ldsX = smem;
  char* ldsW = smem + 16384;
  const int tid = threadIdx.x;
  const int l = tid & 63;
  const int w = tid >> 6, wm = w >> 1, wn = w & 1;
  const int m0 = blockIdx.x * 128, n0 = blockIdx.y * 64;

  int aoff[2][2], boff[2][2];
  #pragma unroll
  for (int mi = 0; mi < 2; mi++){
    int r = wm*32 + mi*16 + (l & 15);
    #pragma unroll
    for (int ks = 0; ks < 2; ks++){
      int c = ks*4 + (l >> 4);
      aoff[mi][ks] = r*128 + ((c ^ (r & 7)) << 4);
    }
  }
  #pragma unroll
  for (int ni = 0; ni < 2; ni++){
    int rr = wn*32 + ni*16 + (l & 15);
    #pragma unroll
    for (int ks = 0; ks < 2; ks++){
      int c = ks*4 + (l >> 4);
      boff[ni][ks] = rr*128 + ((c ^ (rr & 7)) << 4);
    }
  }

  f32x4 acc[2][2] = {};
  for (int kt = 0; kt < 8; kt++){
    const int k0 = kt << 6;
    #pragma unroll
    for (int it = 0; it < 2; it++){
      int g = it*512 + tid;
      int row = g >> 3, c = g & 7, cs = c ^ (row & 7);
      gload16(Xb + (size_t)(m0 + row)*UN + k0 + cs*8, ldsX + g*16);
    }
    {
      int g = tid;
      int row = g >> 3, c = g & 7, cs = c ^ (row & 7);
      gload16(Wob + (size_t)(n0 + row)*UN + k0 + cs*8, ldsW + g*16);
    }
    __syncthreads();
    bf16x8 a[2][2], b[2][2];
    #pragma unroll
    for (int mi = 0; mi < 2; mi++){
      a[mi][0] = *(const bf16x8*)(ldsX + aoff[mi][0]);
      a[mi][1] = *(const bf16x8*)(ldsX + aoff[mi][1]);
    }
    #pragma unroll
    for (int ni = 0; ni < 2; ni++){
      b[ni][0] = *(const bf16x8*)(ldsW + boff[ni][0]);
      b[ni][1] = *(const bf16x8*)(ldsW + boff[ni][1]);
    }
    #pragma unroll
    for (int mi = 0; mi < 2; mi++)
      #pragma unroll
      for (int ni = 0; ni < 2; ni++){
        acc[mi][ni] = __builtin_amdgcn_mfma_f32_16x16x32_bf16(a[mi][0], b[ni][0], acc[mi][ni], 0, 0, 0);
        acc[mi][ni] = __builtin_amdgcn_mfma_f32_16x16x32_bf16(a[mi][1], b[ni][1], acc[mi][ni], 0, 0, 0);
      }
    __syncthreads();
  }

  #pragma unroll
  for (int ni = 0; ni < 2; ni++){
    int n = n0 + wn*32 + ni*16 + (l & 15);
    if (n < NA){
      float bv = bout[n];
      #pragma unroll
      for (int mi = 0; mi < 2; mi++)
        #pragma unroll
        for (int reg = 0; reg < 4; reg++){
          int m = m0 + wm*32 + mi*16 + ((l >> 4) << 2) + reg;
          out[(size_t)m*NA + n] = acc[mi][ni][reg] + bv;
        }
    }
  }
}

extern "C" void kernel_launch(void* const* d_in, const int* in_sizes, int n_in,
                              void* d_out, int out_size, void* d_ws, size_t ws_size,
                              hipStream_t stream)
{
  const float* x     = (const float*)d_in[0];
  const float* style = (const float*)d_in[1];
  const float* Wsl   = (const float*)d_in[2];
  const float* bsl   = (const float*)d_in[3];
  const float* Ws0   = (const float*)d_in[4];
  const float* bs0   = (const float*)d_in[5];
  const float* Ws1   = (const float*)d_in[6];
  const float* bs1   = (const float*)d_in[7];
  const float* Ws2   = (const float*)d_in[8];
  const float* bs2   = (const float*)d_in[9];
  const float* Wih0  = (const float*)d_in[10];
  const float* bih0  = (const float*)d_in[12];
  const float* bhh0  = (const float*)d_in[13];
  const float* Wih1  = (const float*)d_in[14];
  const float* bih1  = (const float*)d_in[16];
  const float* bhh1  = (const float*)d_in[17];
  const float* Wih2  = (const float*)d_in[18];
  const float* bih2  = (const float*)d_in[20];
  const float* bhh2  = (const float*)d_in[21];
  const float* Wout  = (const float*)d_in[22];
  const float* bout  = (const float*)d_in[23];
  // Whh0/1/2 (d_in[11,15,19]) are dead: h_prev == 0 in the reference.

  char* ws = (char*)d_ws;
  float* out = (float*)d_out;
  float* h0 = out + (size_t)B_SZ*NA;
  float* c0 = h0 + (size_t)B_SZ*UN;
  float* h1 = c0 + (size_t)B_SZ*UN;
  float* c1 = h1 + (size_t)B_SZ*UN;
  float* h2 = c1 + (size_t)B_SZ*UN;
  float* c2 = h2 + (size_t)B_SZ*UN;

  prep_kernel<<<1024, 256, 0, stream>>>(Wih0, Wih1, Wih2, Wout,
                                        bih0, bhh0, bih1, bhh1, bih2, bhh2,
                                        Wsl, bsl, Ws0, bs0, Ws1, bs1, Ws2, bs2, ws);

  b0_kernel<<<2048, 256, 0, stream>>>(x, style,
                                      (const float*)(ws + OFF_A0), (const float*)(ws + OFF_C0),
                                      (ushort_t*)(ws + OFF_XA));

  gates_kernel<0><<<dim3(128, 8), 512, 0, stream>>>(
      (const ushort_t*)(ws + OFF_XA), NAP,
      (const ushort_t*)(ws + OFF_WB0), (const float*)(ws + OFF_B0R),
      h0, c0, style,
      (const float*)(ws + OFF_A1), (const float*)(ws + OFF_C1),
      nullptr, nullptr, (ushort_t*)(ws + OFF_XB));

  gates_kernel<1><<<dim3(128, 8), 512, 0, stream>>>(
      (const ushort_t*)(ws + OFF_XB), UN,
      (const ushort_t*)(ws + OFF_WB1), (const float*)(ws + OFF_B1R),
      h1, c1, style,
      (const float*)(ws + OFF_A2), (const float*)(ws + OFF_C2),
      h0, nullptr, (ushort_t*)(ws + OFF_XA));

  gates_kernel<2><<<dim3(128, 8), 512, 0, stream>>>(
      (const ushort_t*)(ws + OFF_XA), UN,
      (const ushort_t*)(ws + OFF_WB2), (const float*)(ws + OFF_B2R),
      h2, c2, nullptr, nullptr, nullptr,
      h0, h1, (ushort_t*)(ws + OFF_XB));

  out_kernel<<<dim3(128, 5), 512, 0, stream>>>(
      (const ushort_t*)(ws + OFF_XB), (const ushort_t*)(ws + OFF_WOB), bout, out);

  (void)in_sizes; (void)n_in; (void)out_size; (void)ws_size;
}

// Round 3
// 444.545 us; speedup vs baseline: 1.0723x; 1.0723x over previous
//
#include <hip/hip_runtime.h>
#include <hip/hip_bf16.h>

#define B_SZ 16384
#define NA 308
#define NAP 320
#define UN 512

typedef float f32x4 __attribute__((ext_vector_type(4)));
typedef short bf16x8 __attribute__((ext_vector_type(8)));
typedef unsigned short ushort_t;

// ---------------- ws layout (bytes) ----------------
constexpr size_t OFF_WB0 = 0;                       // 1536*320*2
constexpr size_t OFF_WB1 = 0x100000;                // 1536*512*2
constexpr size_t OFF_WB2 = 0x280000;
constexpr size_t OFF_WOB = 0x400000;                // 320*512*2
constexpr size_t OFF_B0R = 0x480000;
constexpr size_t OFF_B1R = OFF_B0R + 0x2000;
constexpr size_t OFF_B2R = OFF_B1R + 0x2000;
constexpr size_t OFF_A0  = OFF_B2R + 0x2000;
constexpr size_t OFF_C0  = OFF_A0  + 0x2000;
constexpr size_t OFF_A1  = OFF_C0  + 0x2000;
constexpr size_t OFF_C1  = OFF_A1  + 0x2000;
constexpr size_t OFF_A2  = OFF_C1  + 0x2000;
constexpr size_t OFF_C2  = OFF_A2  + 0x2000;
constexpr size_t OFF_XA  = 0x500000;                // 16 MiB
constexpr size_t OFF_XB  = OFF_XA + 0x1000000;      // 16 MiB

__device__ __forceinline__ float sigmoidf_(float x){ return 1.0f/(1.0f+__expf(-x)); }
__device__ __forceinline__ float tanhf_(float x){ return 2.0f/(1.0f+__expf(-2.0f*x)) - 1.0f; }

__device__ __forceinline__ ushort_t f2b(float f){
  union { float f; unsigned int u; } v; v.f = f;
  unsigned int r = v.u + 0x7FFFu + ((v.u >> 16) & 1u);
  return (ushort_t)(r >> 16);
}

__device__ __forceinline__ void gload16(const void* g, void* l){
  __builtin_amdgcn_global_load_lds((__attribute__((address_space(1))) void*)(g),
                                   (__attribute__((address_space(3))) void*)(l), 16, 0, 0);
}

__device__ __forceinline__ int gate_srow(int n){
  int jb = n / 192; int rem = n - jb*192; int t = rem >> 6; int r = rem & 63;
  int g = (t == 0) ? 0 : ((t == 1) ? 1024 : 1536);   // i,f,g,o ; f dead (c_prev=0)
  return g + jb*64 + r;
}

// ---------------- prep ----------------
__global__ void prep_kernel(
    const float* __restrict__ Wih0, const float* __restrict__ Wih1, const float* __restrict__ Wih2,
    const float* __restrict__ Wout,
    const float* __restrict__ bih0, const float* __restrict__ bhh0,
    const float* __restrict__ bih1, const float* __restrict__ bhh1,
    const float* __restrict__ bih2, const float* __restrict__ bhh2,
    const float* __restrict__ Wsl, const float* __restrict__ bsl,
    const float* __restrict__ Ws0, const float* __restrict__ bs0,
    const float* __restrict__ Ws1, const float* __restrict__ bs1,
    const float* __restrict__ Ws2, const float* __restrict__ bs2,
    char* __restrict__ ws)
{
  const int tid = blockIdx.x*blockDim.x + threadIdx.x;
  const int stride = gridDim.x*blockDim.x;

  const float* WihA[3] = {Wih0, Wih1, Wih2};
  const float* bihA[3] = {bih0, bih1, bih2};
  const float* bhhA[3] = {bhh0, bhh1, bhh2};
  const float* WsA[3]  = {Ws0, Ws1, Ws2};
  const float* bsA[3]  = {bs0, bs1, bs2};
  const int KpA[3] = {NAP, UN, UN};
  const int KrA[3] = {NA, UN, UN};
  const size_t wbOff[3] = {OFF_WB0, OFF_WB1, OFF_WB2};
  const size_t bOff[3]  = {OFF_B0R, OFF_B1R, OFF_B2R};
  const size_t aOff[3]  = {OFF_A0, OFF_A1, OFF_A2};
  const size_t cOff[3]  = {OFF_C0, OFF_C1, OFF_C2};

  #pragma unroll
  for (int ly = 0; ly < 3; ly++){
    ushort_t* dst = (ushort_t*)(ws + wbOff[ly]);
    const float* Wih = WihA[ly];
    const int Kp = KpA[ly], Kr = KrA[ly];
    const int tot = 1536*Kp;
    for (int i = tid; i < tot; i += stride){
      int n = i / Kp, k = i - n*Kp;
      int srow = gate_srow(n);
      float v = (k < Kr) ? Wih[(size_t)srow*Kr + k] : 0.0f;
      dst[i] = f2b(v);
    }
  }
  {
    ushort_t* dst = (ushort_t*)(ws + OFF_WOB);
    for (int i = tid; i < 320*512; i += stride){
      int n = i >> 9, k = i & 511;
      dst[i] = f2b(n < NA ? Wout[(size_t)n*UN + k] : 0.0f);
    }
  }
  #pragma unroll
  for (int ly = 0; ly < 3; ly++){
    float* bd = (float*)(ws + bOff[ly]);
    for (int i = tid; i < 1536; i += stride){
      int srow = gate_srow(i);
      bd[i] = bihA[ly][srow] + bhhA[ly][srow];
    }
  }
  #pragma unroll
  for (int ly = 0; ly < 3; ly++){
    float* Ad = (float*)(ws + aOff[ly]);
    float* cd = (float*)(ws + cOff[ly]);
    const float* Wsp = WsA[ly]; const float* bsp = bsA[ly];
    const int N = (ly == 0) ? NA : UN;
    for (int i = tid; i < N*4; i += stride){
      int n = i >> 2, q = i & 3;
      float s = 0.f;
      #pragma unroll 8
      for (int j = 0; j < 32; j++) s += Wsp[n*32 + j] * Wsl[j*4 + q];
      Ad[i] = s;
    }
    for (int i = tid; i < N; i += stride){
      float s = 0.f;
      #pragma unroll 8
      for (int j = 0; j < 32; j++) s += Wsp[i*32 + j] * bsl[j];
      cd[i] = s + bsp[i];
    }
  }
}

// ---------------- b0: x0 = bf16(x + tanh(style·A0 + c0)) padded to 320 ----------------
__global__ void b0_kernel(const float* __restrict__ x, const float* __restrict__ style,
                          const float* __restrict__ A0, const float* __restrict__ c0,
                          ushort_t* __restrict__ x0b)
{
  int idx = blockIdx.x*blockDim.x + threadIdx.x;
  const int total = B_SZ * (NAP/8);
  const int stride = gridDim.x*blockDim.x;
  for (int i = idx; i < total; i += stride){
    int b = i / 40;
    int kc = (i - b*40) * 8;
    float4 sty = *(const float4*)(style + b*4);
    unsigned int pk[4];
    #pragma unroll
    for (int h = 0; h < 4; h++){
      ushort_t lo = 0, hi = 0;
      int k0 = kc + h*2;
      if (k0 < NA){
        float4 A = *(const float4*)(A0 + k0*4);
        float tt = sty.x*A.x + sty.y*A.y + sty.z*A.z + sty.w*A.w + c0[k0];
        lo = f2b(x[(size_t)b*NA + k0] + tanhf_(tt));
      }
      if (k0 + 1 < NA){
        float4 A = *(const float4*)(A0 + (k0+1)*4);
        float tt = sty.x*A.x + sty.y*A.y + sty.z*A.z + sty.w*A.w + c0[k0+1];
        hi = f2b(x[(size_t)b*NA + k0 + 1] + tanhf_(tt));
      }
      pk[h] = (unsigned int)lo | ((unsigned int)hi << 16);
    }
    *(uint4*)(x0b + (size_t)i*8) = make_uint4(pk[0], pk[1], pk[2], pk[3]);
  }
}

// ---------------- gates GEMM, double-buffered pipeline + LDS-staged coalesced epilogue ----------------
// MODE 0: xnext = h + tanh(style·Anext + cnext)
// MODE 1: xnext = h + hp0 + tanh(style·Anext + cnext)
// MODE 2: xnext = h + hp0 + hp1
template<int MODE>
__global__ __launch_bounds__(512, 4)
void gates_kernel(const ushort_t* __restrict__ Xb, int Kpad,
                  const ushort_t* __restrict__ Wb,       // [8][3][64][Kpad] bf16
                  const float* __restrict__ biasr,       // [8][3][64]
                  float* __restrict__ h_out, float* __restrict__ c_out,
                  const float* __restrict__ style,
                  const float* __restrict__ Anext, const float* __restrict__ cnext,
                  const float* __restrict__ hp0, const float* __restrict__ hp1,
                  ushort_t* __restrict__ xnext)
{
  __shared__ char smem[81920];   // 2 x 40KB pipeline bufs; epilogue reuses as 2 x [128][68] f32

  const int tid = threadIdx.x;
  const int l = tid & 63;
  const int w = tid >> 6;          // 8 waves: 4 (rows) x 2 (j-cols)
  const int wm = w >> 1, wn = w & 1;
  const int m0 = blockIdx.x * 128;
  const int jb = blockIdx.y;

  // fragment LDS offsets (relative to buf base). swizzle: granule c -> c ^ (row&7)
  int aoff[2][2], boff[3][2][2];
  #pragma unroll
  for (int mi = 0; mi < 2; mi++){
    int r = wm*32 + mi*16 + (l & 15);
    #pragma unroll
    for (int ks = 0; ks < 2; ks++){
      int c = ks*4 + (l >> 4);
      aoff[mi][ks] = r*128 + ((c ^ (r & 7)) << 4);
    }
  }
  #pragma unroll
  for (int t = 0; t < 3; t++)
    #pragma unroll
    for (int ni = 0; ni < 2; ni++){
      int rr = t*64 + wn*32 + ni*16 + (l & 15);
      #pragma unroll
      for (int ks = 0; ks < 2; ks++){
        int c = ks*4 + (l >> 4);
        boff[t][ni][ks] = rr*128 + ((c ^ (rr & 7)) << 4);
      }
    }

  f32x4 acc[3][2][2] = {};
  const int KT = Kpad >> 6;

  auto stage = [&](int buf, int kt){
    char* bX = smem + buf*40960;
    char* bW = bX + 16384;
    const int k0 = kt << 6;
    #pragma unroll
    for (int it = 0; it < 2; it++){
      int g = it*512 + tid;
      int row = g >> 3, c = g & 7, cs = c ^ (row & 7);
      gload16(Xb + (size_t)(m0 + row)*Kpad + k0 + cs*8, bX + g*16);
    }
    #pragma unroll
    for (int it = 0; it < 3; it++){
      int g = it*512 + tid;
      int row = g >> 3, c = g & 7, cs = c ^ (row & 7);
      gload16(Wb + (size_t)(jb*192 + row)*Kpad + k0 + cs*8, bW + g*16);
    }
  };

  stage(0, 0);
  __syncthreads();                 // drains vmcnt(0): tile 0 resident
  int cur = 0;
  for (int kt = 0; kt < KT; kt++){
    if (kt + 1 < KT) stage(cur ^ 1, kt + 1);   // prefetch next tile (overlaps MFMA below)
    const char* bX = smem + cur*40960;
    const char* bW = bX + 16384;

    bf16x8 a[2][2];
    #pragma unroll
    for (int mi = 0; mi < 2; mi++)
      #pragma unroll
      for (int ks = 0; ks < 2; ks++)
        a[mi][ks] = *(const bf16x8*)(bX + aoff[mi][ks]);

    #pragma unroll
    for (int t = 0; t < 3; t++){
      bf16x8 bb[2][2];
      #pragma unroll
      for (int ni = 0; ni < 2; ni++)
        #pragma unroll
        for (int ks = 0; ks < 2; ks++)
          bb[ni][ks] = *(const bf16x8*)(bW + boff[t][ni][ks]);
      #pragma unroll
      for (int mi = 0; mi < 2; mi++)
        #pragma unroll
        for (int ni = 0; ni < 2; ni++){
          acc[t][mi][ni] = __builtin_amdgcn_mfma_f32_16x16x32_bf16(a[mi][0], bb[ni][0], acc[t][mi][ni], 0, 0, 0);
          acc[t][mi][ni] = __builtin_amdgcn_mfma_f32_16x16x32_bf16(a[mi][1], bb[ni][1], acc[t][mi][ni], 0, 0, 0);
        }
    }
    __syncthreads();               // drains prefetch vmcnt + all ds_reads of cur
    cur ^= 1;
  }

  // ---- epilogue: activations -> LDS [128][68] f32, then full-line coalesced stores ----
  float* lbH = (float*)smem;
  float* lbC = (float*)(smem + 34816);

  #pragma unroll
  for (int ni = 0; ni < 2; ni++){
    int jl = wn*32 + ni*16 + (l & 15);
    float bi = biasr[jb*192 + jl];
    float bg = biasr[jb*192 + 64 + jl];
    float bo = biasr[jb*192 + 128 + jl];
    #pragma unroll
    for (int mi = 0; mi < 2; mi++)
      #pragma unroll
      for (int reg = 0; reg < 4; reg++){
        int rl = wm*32 + mi*16 + ((l >> 4) << 2) + reg;
        float gi = acc[0][mi][ni][reg] + bi;
        float gg = acc[1][mi][ni][reg] + bg;
        float go = acc[2][mi][ni][reg] + bo;
        float iv = sigmoidf_(gi);
        float gv = tanhf_(gg);
        float ov = sigmoidf_(go);
        float cv = iv * gv;              // c_prev = 0 -> f-gate dead
        float hv = ov * tanhf_(cv);
        lbH[rl*68 + jl] = hv;
        lbC[rl*68 + jl] = cv;
      }
  }
  __syncthreads();

  // h/c: 16 lanes x float4 = 256B contiguous per row
  #pragma unroll
  for (int q = 0; q < 4; q++){
    int idx = q*512 + tid;
    int r = idx >> 4, c4 = idx & 15;
    size_t go = (size_t)(m0 + r)*UN + jb*64 + c4*4;
    *(float4*)(h_out + go) = *(const float4*)(lbH + r*68 + c4*4);
    *(float4*)(c_out + go) = *(const float4*)(lbC + r*68 + c4*4);
  }

  // xnext: 8 bf16 (16B) per lane, residuals + style read coalesced here
  #pragma unroll
  for (int q = 0; q < 2; q++){
    int idx = q*512 + tid;
    int r = idx >> 3, c8 = idx & 7;
    int m = m0 + r;
    const float* hp = lbH + r*68 + c8*8;
    float hv8[8];
    *(float4*)(hv8)     = *(const float4*)(hp);
    *(float4*)(hv8 + 4) = *(const float4*)(hp + 4);
    float nx[8];
    if constexpr (MODE == 0 || MODE == 1){
      float4 sty = *(const float4*)(style + (size_t)m*4);
      #pragma unroll
      for (int e = 0; e < 8; e++){
        int j = jb*64 + c8*8 + e;
        float4 An = *(const float4*)(Anext + (size_t)j*4);
        float tt = sty.x*An.x + sty.y*An.y + sty.z*An.z + sty.w*An.w + cnext[j];
        nx[e] = hv8[e] + tanhf_(tt);
      }
      if constexpr (MODE == 1){
        const float* p = hp0 + (size_t)m*UN + jb*64 + c8*8;
        float4 p0 = *(const float4*)(p), p1 = *(const float4*)(p + 4);
        nx[0]+=p0.x; nx[1]+=p0.y; nx[2]+=p0.z; nx[3]+=p0.w;
        nx[4]+=p1.x; nx[5]+=p1.y; nx[6]+=p1.z; nx[7]+=p1.w;
      }
    } else {
      const float* p = hp0 + (size_t)m*UN + jb*64 + c8*8;
      const float* s = hp1 + (size_t)m*UN + jb*64 + c8*8;
      float4 p0 = *(const float4*)(p), p1 = *(const float4*)(p + 4);
      float4 q0 = *(const float4*)(s), q1 = *(const float4*)(s + 4);
      nx[0]=hv8[0]+p0.x+q0.x; nx[1]=hv8[1]+p0.y+q0.y; nx[2]=hv8[2]+p0.z+q0.z; nx[3]=hv8[3]+p0.w+q0.w;
      nx[4]=hv8[4]+p1.x+q1.x; nx[5]=hv8[5]+p1.y+q1.y; nx[6]=hv8[6]+p1.z+q1.z; nx[7]=hv8[7]+p1.w+q1.w;
    }
    union { ushort_t u[8]; uint4 v; } pk;
    #pragma unroll
    for (int e = 0; e < 8; e++) pk.u[e] = f2b(nx[e]);
    *(uint4*)(xnext + (size_t)m*UN + jb*64 + c8*8) = pk.v;
  }
}

// ---------------- out = Xf @ Wout.T + bout, same pipeline + coalesced epilogue ----------------
__global__ __launch_bounds__(512, 4)
void out_kernel(const ushort_t* __restrict__ Xb,
                const ushort_t* __restrict__ Wob,   // [320][512] bf16 (rows >=308 zero)
                const float* __restrict__ bout,
                float* __restrict__ out)
{
  __shared__ char smem[49152];   // 2 x 24KB bufs; epilogue [128][68] f32 = 34816B
  const int tid = threadIdx.x;
  const int l = tid & 63;
  const int w = tid >> 6, wm = w >> 1, wn = w & 1;
  const int m0 = blockIdx.x * 128, n0 = blockIdx.y * 64;

  int aoff[2][2], boff[2][2];
  #pragma unroll
  for (int mi = 0; mi < 2; mi++){
    int r = wm*32 + mi*16 + (l & 15);
    #pragma unroll
    for (int ks = 0; ks < 2; ks++){
      int c = ks*4 + (l >> 4);
      aoff[mi][ks] = r*128 + ((c ^ (r & 7)) << 4);
    }
  }
  #pragma unroll
  for (int ni = 0; ni < 2; ni++){
    int rr = wn*32 + ni*16 + (l & 15);
    #pragma unroll
    for (int ks = 0; ks < 2; ks++){
      int c = ks*4 + (l >> 4);
      boff[ni][ks] = rr*128 + ((c ^ (rr & 7)) << 4);
    }
  }

  f32x4 acc[2][2] = {};

  auto stage = [&](int buf, int kt){
    char* bX = smem + buf*24576;
    char* bW = bX + 16384;
    const int k0 = kt << 6;
    #pragma unroll
    for (int it = 0; it < 2; it++){
      int g = it*512 + tid;
      int row = g >> 3, c = g & 7, cs = c ^ (row & 7);
      gload16(Xb + (size_t)(m0 + row)*UN + k0 + cs*8, bX + g*16);
    }
    {
      int g = tid;
      int row = g >> 3, c = g & 7, cs = c ^ (row & 7);
      gload16(Wob + (size_t)(n0 + row)*UN + k0 + cs*8, bW + g*16);
    }
  };

  stage(0, 0);
  __syncthreads();
  int cur = 0;
  for (int kt = 0; kt < 8; kt++){
    if (kt + 1 < 8) stage(cur ^ 1, kt + 1);
    const char* bX = smem + cur*24576;
    const char* bW = bX + 16384;
    bf16x8 a[2][2], b[2][2];
    #pragma unroll
    for (int mi = 0; mi < 2; mi++){
      a[mi][0] = *(const bf16x8*)(bX + aoff[mi][0]);
      a[mi][1] = *(const bf16x8*)(bX + aoff[mi][1]);
    }
    #pragma unroll
    for (int ni = 0; ni < 2; ni++){
      b[ni][0] = *(const bf16x8*)(bW + boff[ni][0]);
      b[ni][1] = *(const bf16x8*)(bW + boff[ni][1]);
    }
    #pragma unroll
    for (int mi = 0; mi < 2; mi++)
      #pragma unroll
      for (int ni = 0; ni < 2; ni++){
        acc[mi][ni] = __builtin_amdgcn_mfma_f32_16x16x32_bf16(a[mi][0], b[ni][0], acc[mi][ni], 0, 0, 0);
        acc[mi][ni] = __builtin_amdgcn_mfma_f32_16x16x32_bf16(a[mi][1], b[ni][1], acc[mi][ni], 0, 0, 0);
      }
    __syncthreads();
    cur ^= 1;
  }

  float* lb = (float*)smem;
  #pragma unroll
  for (int ni = 0; ni < 2; ni++){
    int nl = wn*32 + ni*16 + (l & 15);
    int n = n0 + nl;
    float bv = (n < NA) ? bout[n] : 0.0f;
    #pragma unroll
    for (int mi = 0; mi < 2; mi++)
      #pragma unroll
      for (int reg = 0; reg < 4; reg++){
        int rl = wm*32 + mi*16 + ((l >> 4) << 2) + reg;
        lb[rl*68 + nl] = acc[mi][ni][reg] + bv;
      }
  }
  __syncthreads();
  #pragma unroll
  for (int q = 0; q < 4; q++){
    int idx = q*512 + tid;
    int r = idx >> 4, c4 = idx & 15;
    int n = n0 + c4*4;
    if (n <= NA - 4)   // 308 % 4 == 0, so runs are whole float4s
      *(float4*)(out + (size_t)(m0 + r)*NA + n) = *(const float4*)(lb + r*68 + c4*4);
  }
}

extern "C" void kernel_launch(void* const* d_in, const int* in_sizes, int n_in,
                              void* d_out, int out_size, void* d_ws, size_t ws_size,
                              hipStream_t stream)
{
  const float* x     = (const float*)d_in[0];
  const float* style = (const float*)d_in[1];
  const float* Wsl   = (const float*)d_in[2];
  const float* bsl   = (const float*)d_in[3];
  const float* Ws0   = (const float*)d_in[4];
  const float* bs0   = (const float*)d_in[5];
  const float* Ws1   = (const float*)d_in[6];
  const float* bs1   = (const float*)d_in[7];
  const float* Ws2   = (const float*)d_in[8];
  const float* bs2   = (const float*)d_in[9];
  const float* Wih0  = (const float*)d_in[10];
  const float* bih0  = (const float*)d_in[12];
  const float* bhh0  = (const float*)d_in[13];
  const float* Wih1  = (const float*)d_in[14];
  const float* bih1  = (const float*)d_in[16];
  const float* bhh1  = (const float*)d_in[17];
  const float* Wih2  = (const float*)d_in[18];
  const float* bih2  = (const float*)d_in[20];
  const float* bhh2  = (const float*)d_in[21];
  const float* Wout  = (const float*)d_in[22];
  const float* bout  = (const float*)d_in[23];
  // Whh0/1/2 (d_in[11,15,19]) are dead: h_prev == 0 in the reference.

  char* ws = (char*)d_ws;
  float* out = (float*)d_out;
  float* h0 = out + (size_t)B_SZ*NA;
  float* c0 = h0 + (size_t)B_SZ*UN;
  float* h1 = c0 + (size_t)B_SZ*UN;
  float* c1 = h1 + (size_t)B_SZ*UN;
  float* h2 = c1 + (size_t)B_SZ*UN;
  float* c2 = h2 + (size_t)B_SZ*UN;

  prep_kernel<<<1024, 256, 0, stream>>>(Wih0, Wih1, Wih2, Wout,
                                        bih0, bhh0, bih1, bhh1, bih2, bhh2,
                                        Wsl, bsl, Ws0, bs0, Ws1, bs1, Ws2, bs2, ws);

  b0_kernel<<<2048, 256, 0, stream>>>(x, style,
                                      (const float*)(ws + OFF_A0), (const float*)(ws + OFF_C0),
                                      (ushort_t*)(ws + OFF_XA));

  gates_kernel<0><<<dim3(128, 8), 512, 0, stream>>>(
      (const ushort_t*)(ws + OFF_XA), NAP,
      (const ushort_t*)(ws + OFF_WB0), (const float*)(ws + OFF_B0R),
      h0, c0, style,
      (const float*)(ws + OFF_A1), (const float*)(ws + OFF_C1),
      nullptr, nullptr, (ushort_t*)(ws + OFF_XB));

  gates_kernel<1><<<dim3(128, 8), 512, 0, stream>>>(
      (const ushort_t*)(ws + OFF_XB), UN,
      (const ushort_t*)(ws + OFF_WB1), (const float*)(ws + OFF_B1R),
      h1, c1, style,
      (const float*)(ws + OFF_A2), (const float*)(ws + OFF_C2),
      h0, nullptr, (ushort_t*)(ws + OFF_XA));

  gates_kernel<2><<<dim3(128, 8), 512, 0, stream>>>(
      (const ushort_t*)(ws + OFF_XA), UN,
      (const ushort_t*)(ws + OFF_WB2), (const float*)(ws + OFF_B2R),
      h2, c2, nullptr, nullptr, nullptr,
      h0, h1, (ushort_t*)(ws + OFF_XB));

  out_kernel<<<dim3(128, 5), 512, 0, stream>>>(
      (const ushort_t*)(ws + OFF_XB), (const ushort_t*)(ws + OFF_WOB), bout, out);

  (void)in_sizes; (void)n_in; (void)out_size; (void)ws_size;
}